// Round 13
// baseline (161.705 us; speedup 1.0000x reference)
//
#include <hip/hip_runtime.h>
#include <hip/hip_fp16.h>
#include <math.h>

// Problem dims (fixed)
#define B     4096
#define NIN   512
#define L     16
#define N     512
#define K     32
#define NOUT  256
#define HID   (L * N)          // 8192
#define TOTAL (NIN + L * N)    // 8704
#define BROWS 8                // batch rows per block (u8 entry = 8 B)
#define BLOCK 512              // one neuron per thread per layer
#define XBASE (TOTAL * 8)            // 69632: start of fp16-x region
#define LDS_BYTES (XBASE + NIN * 16) // 77824 -> 2 blocks/CU (163840/2=81920)

typedef __attribute__((ext_vector_type(2))) _Float16 hv2;       // 4 B: 2 fp16
typedef __attribute__((ext_vector_type(2))) unsigned int u32x2; // 8 B
typedef __attribute__((ext_vector_type(4))) unsigned int u32x4; // 16 B
typedef __attribute__((ext_vector_type(8))) _Float16 h8;        // 16 B: 8 fp16

// x-u8 quantization: stored = round((x+5.5)*(255/11)); dequant folded into
// w' and the f32 bias at repack.
#define XSCL (255.0f / 11.0f)
#define XOFF 5.5f

__device__ __forceinline__ float sigmoidf_fast(float z) {
    return 1.0f / (1.0f + __expf(-z));
}

// fp16x2 dot with f32 accumulate: v_dot2_f32_f16 (products fp16, sum f32 —
// the proven round-12 numerics).
__device__ __forceinline__ float fdot2f(hv2 a, hv2 b, float c) {
#if defined(__has_builtin) && __has_builtin(__builtin_amdgcn_fdot2)
    return __builtin_amdgcn_fdot2(a, b, c, false);
#else
    return fmaf((float)a.x, (float)b.x, fmaf((float)a.y, (float)b.y, c));
#endif
}

// ---- repack v5 (BYTE-IDENTICAL to round 12 — proven): pack
// (idx<<16 | fp16 w'); fold all affine corrections into the f32 bias using
// the fp16-ROUNDED w' so the kernel's 0x6400 trick cancels exactly:
//   layer-0 neurons (all idx < NIN): w' = w            (fp16-x path, no 1024)
//   deeper, idx <  NIN (x-u8):   w' = w*11/255; bias -= 1024*w'_h + 5.5*w
//   deeper, idx >= NIN (hidden): w' = w/255;    bias -= 1024*w'_h
__global__ __launch_bounds__(64)
void repack_kernel(const float* __restrict__ W,
                   const int*   __restrict__ idx,
                   const float* __restrict__ W_out,
                   const int*   __restrict__ idx_out,
                   const float* __restrict__ b,
                   const float* __restrict__ b_out,
                   unsigned* __restrict__ packed,
                   float*    __restrict__ biasw)
{
    const int n = blockIdx.x * 64 + threadIdx.x;   // grid*64 == 8448 exactly
    const int* ip; const float* wp; float bb;
    if (n < HID) {
        ip = idx + (size_t)n * K;  wp = W + (size_t)n * K;  bb = b[n];
    } else {
        const int m = n - HID;
        ip = idx_out + (size_t)m * K;  wp = W_out + (size_t)m * K;  bb = b_out[m];
    }
    const bool l0 = (n < N);                       // layer-0 neuron
    unsigned* po = packed + (size_t)n * K;

#pragma unroll
    for (int q = 0; q < 8; ++q) {
        const int4   a = ((const int4*)ip)[q];
        const float4 f = ((const float4*)wp)[q];
        const int   cc[4] = {a.x, a.y, a.z, a.w};
        const float ww[4] = {f.x, f.y, f.z, f.w};
#pragma unroll
        for (int kq = 0; kq < 4; ++kq) {
            const int c = cc[kq]; const float w = ww[kq];
            float wprime;
            if (l0)            { wprime = w; }
            else if (c < NIN)  { wprime = w * (11.0f / 255.0f); }
            else               { wprime = w * (1.0f / 255.0f); }
            const _Float16 wh_ = (_Float16)wprime;
            if (!l0) {
                bb -= 1024.0f * (float)wh_;        // cancels the 0x6400 offset
                if (c < NIN) bb -= XOFF * w;       // x-u8 zero-point
            }
            po[q * 4 + kq] =
                ((unsigned)c << 16) | __builtin_bit_cast(unsigned short, wh_);
        }
    }
    biasw[n] = bb;
}

// ---- gather 8 u8 entries (ds_read_b64, addr = idx*8 from packed hi16;
// uniform for hidden AND output layers at 8 B entries)
#define GATH8(PW, Q0, D)                                                      \
    _Pragma("unroll")                                                         \
    for (int jj = 0; jj < 8; ++jj) {                                          \
        const unsigned u = (PW)[((Q0) + jj) >> 2][((Q0) + jj) & 3];           \
        const int ad = (int)((u >> 16) << 3);                                 \
        (D)[jj] = *(const u32x2*)(lds + ad);                                  \
    }

// ---- item-pair dot (round-12 proven marshal, 2 dwords = 8 rows):
// perm builds {1024+vj[r], 1024+vj1[r]} (sel 0x0C = const 0x00 byte), or
// 0x64006400 (byte v | 0x6400 IS fp16(1024+v)), fdot2 into the f32 row acc.
#define FDOT_PAIR(UJ, UJ1, DJ, DJ1, FA)                                       \
    {                                                                         \
        const hv2 w2_ = __builtin_bit_cast(hv2,                               \
            __builtin_amdgcn_perm((UJ1), (UJ), 0x05040100u));                 \
        _Pragma("unroll")                                                     \
        for (int d_ = 0; d_ < 2; ++d_) {                                      \
            _Pragma("unroll")                                                 \
            for (int r_ = 0; r_ < 4; ++r_) {                                  \
                const unsigned pb_ = __builtin_amdgcn_perm(                   \
                    (DJ1)[d_], (DJ)[d_],                                      \
                    0x0C000C00u | ((unsigned)(4 + r_) << 16) | (unsigned)r_)  \
                    | 0x64006400u;                                            \
                (FA)[4 * d_ + r_] = fdot2f(                                   \
                    __builtin_bit_cast(hv2, pb_), w2_, (FA)[4 * d_ + r_]);    \
            }                                                                 \
        }                                                                     \
    }

#define FDOT_BATCH(PW, Q0, D, FA)                                             \
    _Pragma("unroll")                                                         \
    for (int m_ = 0; m_ < 4; ++m_) {                                          \
        const unsigned uj_  = (PW)[((Q0) + 2 * m_) >> 2][((Q0) + 2 * m_) & 3];\
        const unsigned uj1_ =                                                 \
            (PW)[((Q0) + 2 * m_ + 1) >> 2][((Q0) + 2 * m_ + 1) & 3];          \
        FDOT_PAIR(uj_, uj1_, (D)[2 * m_], (D)[2 * m_ + 1], FA)                \
    }

// ---- epilogue: bias + sigmoid + u8 quantize + one ds_write_b64
#define EPI(FA, BB, ENT)                                                      \
    {                                                                         \
        u32x2 ow;                                                             \
        _Pragma("unroll")                                                     \
        for (int i2 = 0; i2 < 2; ++i2) {                                      \
            unsigned dw = 0;                                                  \
            _Pragma("unroll")                                                 \
            for (int j2 = 0; j2 < 4; ++j2) {                                  \
                const float sg = sigmoidf_fast((FA)[4 * i2 + j2] + (BB));     \
                dw |= ((unsigned)fmaf(sg, 255.f, 0.5f)) << (8 * j2);          \
            }                                                                 \
            ow[i2] = dw;                                                      \
        }                                                                     \
        *(u32x2*)(lds + (size_t)(ENT) * 8) = ow;                              \
    }

// 2-batch staging window (register pressure: <=2 batches of 8x2 dwords live)
#define LAYERU8BODY(PW, FA)                                                   \
    u32x2 d0[8], d1[8], d2[8], d3[8];                                         \
    _Pragma("unroll") for (int i0 = 0; i0 < 8; ++i0) (FA)[i0] = 0.f;          \
    GATH8(PW, 0, d0) GATH8(PW, 8, d1)                                         \
    FDOT_BATCH(PW, 0, d0, FA)                                                 \
    GATH8(PW, 16, d2)                                                         \
    FDOT_BATCH(PW, 8, d1, FA)                                                 \
    GATH8(PW, 24, d3)                                                         \
    FDOT_BATCH(PW, 16, d2, FA)                                                \
    FDOT_BATCH(PW, 24, d3, FA)

#define LAYERU8(PW, BB, ENT)                                                  \
    {                                                                         \
        float fa[8];                                                          \
        LAYERU8BODY(PW, fa)                                                   \
        EPI(fa, BB, ENT)                                                      \
    }

// ---- layer 0: fp16-x entries (16 B = 8 rows), item-pair perms + fdot2,
// no 0x6400. Dword p of the entry = rows (2p, 2p+1).
#define L0PAIR(UJ, UJ1, LWJ, LWJ1, FA)                                        \
    {                                                                         \
        const hv2 w2_ = __builtin_bit_cast(hv2,                               \
            __builtin_amdgcn_perm((UJ1), (UJ), 0x05040100u));                 \
        _Pragma("unroll")                                                     \
        for (int p_ = 0; p_ < 4; ++p_) {                                      \
            const unsigned pe_ = __builtin_amdgcn_perm(                       \
                (LWJ1)[p_], (LWJ)[p_], 0x05040100u);                          \
            const unsigned po_ = __builtin_amdgcn_perm(                       \
                (LWJ1)[p_], (LWJ)[p_], 0x07060302u);                          \
            (FA)[2 * p_]     = fdot2f(__builtin_bit_cast(hv2, pe_), w2_,      \
                                      (FA)[2 * p_]);                          \
            (FA)[2 * p_ + 1] = fdot2f(__builtin_bit_cast(hv2, po_), w2_,      \
                                      (FA)[2 * p_ + 1]);                      \
        }                                                                     \
    }

#define LAYER0(PW, BB, ENT)                                                   \
    {                                                                         \
        float fa[8];                                                          \
        _Pragma("unroll") for (int i0 = 0; i0 < 8; ++i0) fa[i0] = 0.f;        \
        _Pragma("unroll")                                                     \
        for (int g = 0; g < 4; ++g) {                                         \
            u32x4 lw[8];                                                      \
            _Pragma("unroll")                                                 \
            for (int j = 0; j < 8; ++j) {                                     \
                const unsigned u = (PW)[(g * 8 + j) >> 2][(g * 8 + j) & 3];   \
                const int ad = XBASE + (int)((u >> 16) << 4);                 \
                lw[j] = *(const u32x4*)(lds + ad);                            \
            }                                                                 \
            _Pragma("unroll")                                                 \
            for (int m = 0; m < 4; ++m) {                                     \
                const unsigned uj =                                           \
                    (PW)[(g * 8 + 2 * m) >> 2][(g * 8 + 2 * m) & 3];          \
                const unsigned uj1 =                                          \
                    (PW)[(g * 8 + 2 * m + 1) >> 2][(g * 8 + 2 * m + 1) & 3];  \
                L0PAIR(uj, uj1, lw[2 * m], lw[2 * m + 1], fa)                 \
            }                                                                 \
        }                                                                     \
        EPI(fa, BB, ENT)                                                      \
    }

// buf: [u8 entries: 8704 x 8 B = 68 KB][fp16-x: 512 x 16 B = 8 KB] = 76 KB
// -> 2 blocks/CU, 16 waves (4/SIMD): 2x the occupancy of round 12 at the
// SAME LDS byte traffic (b64 streams at the b128 byte rate; b32 is the
// half-rate trap, round 6) and the SAME total VALU ops (half per thread,
// twice the waves). Targets the 34% bubble term, not the pipes.
__global__ __launch_bounds__(BLOCK, 4)
void ffnet_kernel(const float* __restrict__ x,
                  const unsigned* __restrict__ packed,
                  const float*    __restrict__ biasw,
                  float* __restrict__ out)
{
    extern __shared__ char lds[];

    const int t  = threadIdx.x;
    const int r0 = blockIdx.x * BROWS;

    // ---- stage x: thread t owns column t (NIN == BLOCK). Dual format:
    // exact fp16 (layer 0) + u8 +-5.5 (incidental deep-layer x-hits).
    {
        float xv[8];
#pragma unroll
        for (int r = 0; r < 8; ++r) xv[r] = x[(size_t)(r0 + r) * NIN + t];
        h8 hx;
#pragma unroll
        for (int r = 0; r < 8; ++r) hx[r] = (_Float16)xv[r];
        *(h8*)(lds + XBASE + t * 16) = hx;
        u32x2 ux;
#pragma unroll
        for (int i = 0; i < 2; ++i) {
            unsigned dw = 0;
#pragma unroll
            for (int j2 = 0; j2 < 4; ++j2) {
                const float q = fminf(
                    fmaxf(fmaf(xv[4 * i + j2] + XOFF, XSCL, 0.5f), 0.f), 255.f);
                dw |= ((unsigned)q) << (8 * j2);
            }
            ux[i] = dw;
        }
        *(u32x2*)(lds + t * 8) = ux;
    }

    // ---- prologue: layer-0 packed (idx|w) + bias
    u32x4 pa[8], pb[8];
    float ba, bb;
    {
        const u32x4* pp = (const u32x4*)(packed + (size_t)t * K);
#pragma unroll
        for (int q = 0; q < 8; ++q) pa[q] = pp[q];
        ba = biasw[t];
    }
    __syncthreads();

    // ---- layer 0 (fp16-x path); prefetch layer 1
    {
        const u32x4* pp = (const u32x4*)(packed + (size_t)(N + t) * K);
#pragma unroll
        for (int q = 0; q < 8; ++q) pb[q] = pp[q];
        bb = biasw[N + t];
    }
    LAYER0(pa, ba, (NIN + t))
    __syncthreads();

    // ---- layers 1..14 (ping-pong), then 15, then output
    for (int l = 1; l < 15; l += 2) {
        {
            const u32x4* pp = (const u32x4*)(packed + (size_t)((l + 1) * N + t) * K);
#pragma unroll
            for (int q = 0; q < 8; ++q) pa[q] = pp[q];
            ba = biasw[(l + 1) * N + t];
        }
        LAYERU8(pb, bb, (NIN + l * N + t))
        __syncthreads();
        {
            const u32x4* pp = (const u32x4*)(packed + (size_t)((l + 2) * N + t) * K);
#pragma unroll
            for (int q = 0; q < 8; ++q) pb[q] = pp[q];
            bb = biasw[(l + 2) * N + t];
        }
        LAYERU8(pa, ba, (NIN + (l + 1) * N + t))
        __syncthreads();
    }

    if (t < NOUT) {   // prefetch output-layer packed + bias
        const u32x4* pp = (const u32x4*)(packed + (size_t)(HID + t) * K);
#pragma unroll
        for (int q = 0; q < 8; ++q) pa[q] = pp[q];
        ba = biasw[HID + t];
    }
    LAYERU8(pb, bb, (NIN + 15 * N + t))
    __syncthreads();

    // ---- output layer: threads 0..NOUT-1, fp32 out (same 8 B addressing)
    if (t < NOUT) {
        float fa[8];
        LAYERU8BODY(pa, fa)
#pragma unroll
        for (int r = 0; r < 8; ++r)
            out[(size_t)(r0 + r) * NOUT + t] = sigmoidf_fast(fa[r] + ba);
    }
}

extern "C" void kernel_launch(void* const* d_in, const int* in_sizes, int n_in,
                              void* d_out, int out_size, void* d_ws, size_t ws_size,
                              hipStream_t stream) {
    const float* x     = (const float*)d_in[0];   // (B, NIN)
    const float* W     = (const float*)d_in[1];   // (L, N, K)
    const float* b     = (const float*)d_in[2];   // (L, N)
    const float* W_out = (const float*)d_in[3];   // (NOUT, K)
    const float* b_out = (const float*)d_in[4];   // (NOUT,)
    const int*   idx   = (const int*)d_in[5];     // (L, N, K)
    const int*   idx_o = (const int*)d_in[6];     // (NOUT, K)
    float* out = (float*)d_out;                   // (B, NOUT)

    // workspace: packed (idx|w') 270336 x 4 B = 1081344, biasw 8448 x 4 B
    // = 33792 -> 1.064 MB total (proven in rounds 10/12)
    char* ws = (char*)d_ws;
    unsigned* packed = (unsigned*)(ws);
    float*    biasw  = (float*)   (ws + 1081344);

    repack_kernel<<<dim3((HID + NOUT) / 64), dim3(64), 0, stream>>>(
        W, idx, W_out, idx_o, b, b_out, packed, biasw);

    ffnet_kernel<<<dim3(B / BROWS), dim3(BLOCK), LDS_BYTES, stream>>>(
        x, packed, biasw, out);
}